// Round 5
// baseline (66.790 us; speedup 1.0000x reference)
//
#include <hip/hip_runtime.h>
#include <math.h>

#define BB 16
#define NN 8400
#define CC 80
#define MM 64
#define KTOP 13
#define FEPS 1e-9f
#define CAP 2048   // max valid anchors per (b,m); worst case ~1500

// ---- output layout (floats) ----
#define OFF_O1 134400
#define OFF_O2 672000
#define OFF_O3 11424000
#define OFF_O4 11558400
// scratch (cnt/msel/asel, 3 x B*N) in the TAIL of the cls region; read by
// k_assign, then fully overwritten by k_cls afterwards (stream order).
#define SCR_OFF 10348800   // 10,752,000 - 3*134,400

__device__ __forceinline__ float iou_pair(const float4 g, const float4 p) {
    float ix1 = fmaxf(g.x, p.x);
    float iy1 = fmaxf(g.y, p.y);
    float ix2 = fminf(g.z, p.z);
    float iy2 = fminf(g.w, p.w);
    float iw = fmaxf(ix2 - ix1, 0.0f);
    float ih = fmaxf(iy2 - iy1, 0.0f);
    float inter = iw * ih;
    float aa = (g.z - g.x) * (g.w - g.y);
    float ab = (p.z - p.x) * (p.w - p.y);
    float uni = fmaxf(aa + ab - inter, FEPS);
    return inter / uni;
}

__global__ __launch_bounds__(256) void k_zero_scratch(int* __restrict__ p, int n)
{
    int i = blockIdx.x * 256 + threadIdx.x;
    if (i < n) p[i] = 0;
}

// Kernel 1: one workgroup per (b,m).
//  pass1 (4 waves): in-box test over anchors (float4), ballot-append indices.
//  pass2 (4 waves): align metric for compacted entries; store unique 64-bit
//                   composite (key<<32)|(NN-n)  -> order-invariant top-k.
//  select (wave 0): 13 rounds of wave argmax+remove, no barriers; emit <=13.
__global__ __launch_bounds__(256) void k_select(
    const float* __restrict__ pd_scores, const float* __restrict__ pd_bboxes,
    const float* __restrict__ anc, const int* __restrict__ gt_labels,
    const float* __restrict__ gt_bboxes, const float* __restrict__ mask_gt,
    int* __restrict__ cntb, int* __restrict__ mselb, float* __restrict__ aselb)
{
    const int bm = blockIdx.x;
    const int b = bm >> 6, m = bm & 63;
    const int tid = threadIdx.x;
    const int lane = tid & 63;
    const int wid = tid >> 6;

    __shared__ unsigned long long k64[CAP];   // 16 KB composites
    __shared__ unsigned short nnidx[CAP];     // 4 KB anchor ids
    __shared__ int scnt;

    const float4 g = *(const float4*)&gt_bboxes[(size_t)bm * 4];
    const int lab  = gt_labels[bm];
    const int labc = lab > 0 ? lab : 0;
    const bool mgb = mask_gt[bm] > 0.5f;
    const unsigned epskey = __float_as_uint(FEPS);

    if (tid == 0) scnt = 0;
    __syncthreads();

    // pass 1: in-box test, 2 anchors per thread-iter, ballot-aggregated append
    const float4* anc4 = (const float4*)anc;   // 4200 entries
    for (int it = 0; it < 17; ++it) {
        int q = it * 256 + tid;
        bool vA = false, vB = false;
        if (q < 4200 && mgb) {
            float4 av = anc4[q];
            {
                float d1 = av.x - g.x, d2 = av.y - g.y;
                float d3 = g.z - av.x, d4 = g.w - av.y;
                vA = fminf(fminf(d1, d2), fminf(d3, d4)) > FEPS;
            }
            {
                float d1 = av.z - g.x, d2 = av.w - g.y;
                float d3 = g.z - av.z, d4 = g.w - av.w;
                vB = fminf(fminf(d1, d2), fminf(d3, d4)) > FEPS;
            }
        }
        unsigned long long balA = __ballot(vA);
        unsigned long long balB = __ballot(vB);
        if (balA | balB) {
            int cA = __popcll(balA);
            int base = 0;
            if (lane == 0) base = atomicAdd(&scnt, cA + __popcll(balB));
            base = __shfl(base, 0, 64);
            unsigned long long below = (1ull << lane) - 1ull;
            if (vA) {
                int s = base + __popcll(balA & below);
                if (s < CAP) nnidx[s] = (unsigned short)(2 * q);
            }
            if (vB) {
                int s = base + cA + __popcll(balB & below);
                if (s < CAP) nnidx[s] = (unsigned short)(2 * q + 1);
            }
        }
    }
    __syncthreads();
    const int count = min(scnt, CAP);

    // pass 2: align metric for compacted entries (~400); composite into k64
    const float* srow = pd_scores + (size_t)b * NN * CC + labc;
    const float* pbb  = pd_bboxes + (size_t)b * NN * 4;
    for (int i = tid; i < count; i += 256) {
        int n = nnidx[i];
        float4 p = *(const float4*)&pbb[(size_t)n * 4];
        float io = iou_pair(g, p);
        float x = srow[(size_t)n * CC];
        float s = 1.0f / (1.0f + expf(-x));
        float i2 = io * io;
        unsigned key = __float_as_uint(s * (i2 * i2 * i2));  // >= 0
        k64[i] = ((unsigned long long)key << 32) | (unsigned)(NN - n);
    }
    __syncthreads();

    // selection: wave 0 only, 13 rounds, wave-synchronous (no block barriers)
    if (wid == 0) {
        unsigned long long winv = 0ull;
        for (int r = 0; r < KTOP; ++r) {
            unsigned long long bv = 0ull; int bs = -1;
            for (int i = lane; i < count; i += 64) {
                unsigned long long e = k64[i];
                if (e > bv) { bv = e; bs = i; }
            }
            #pragma unroll
            for (int off = 32; off > 0; off >>= 1) {
                unsigned long long ov = __shfl_xor(bv, off, 64);
                int os = __shfl_xor(bs, off, 64);
                if (ov > bv) { bv = ov; bs = os; }
            }
            // all lanes agree on (bv, bs); composites are unique (n unique)
            if (bs >= 0) k64[bs] = 0ull;     // same-addr write by all lanes
            if (lane == r) winv = bv;        // lane r keeps round-r winner
            asm volatile("" ::: "memory");
        }
        if (lane < KTOP) {
            unsigned hk = (unsigned)(winv >> 32);
            if (hk > epskey) {               // positive floats: uint order == float order
                int n = NN - (int)(winv & 0xFFFFFFFFull);
                int ai = b * NN + n;
                atomicAdd(&cntb[ai], 1);
                atomicAdd(&mselb[ai], m);
                atomicAdd(&aselb[ai], __uint_as_float(hk));
            }
        }
    }
}

// Kernel 2: one thread per (b,n). Resolve assignment from scattered positives.
__global__ __launch_bounds__(256) void k_assign(
    const float* __restrict__ pd_scores, const float* __restrict__ pd_bboxes,
    const float* __restrict__ anc, const int* __restrict__ gt_labels,
    const float* __restrict__ gt_bboxes, const float* __restrict__ mask_gt,
    const int* __restrict__ cntb, const int* __restrict__ mselb,
    const float* __restrict__ aselb,
    float* __restrict__ out0, float* __restrict__ out1,
    float* __restrict__ out3, float* __restrict__ out4,
    float* __restrict__ perb)
{
    const int b = blockIdx.y;
    const int n = blockIdx.x * 256 + threadIdx.x;

    __shared__ float4 gtb[MM];
    __shared__ int    labS[MM];
    __shared__ float  mgS[MM];
    if (threadIdx.x < MM) {
        int m = threadIdx.x;
        gtb[m]  = *(const float4*)&gt_bboxes[(size_t)(b * MM + m) * 4];
        labS[m] = gt_labels[b * MM + m];
        mgS[m]  = mask_gt[b * MM + m];
    }
    __syncthreads();
    if (n >= NN) return;

    const size_t idx = (size_t)b * NN + n;
    const int cnt = cntb[idx];

    float per = 0.0f, fg = 0.0f;
    int mstar = 0;

    if (cnt > 0) {
        fg = 1.0f;
        const float4 p = *(const float4*)&pd_bboxes[idx * 4];
        if (cnt == 1) {
            mstar = mselb[idx];
            float a = aselb[idx];
            float io = iou_pair(gtb[mstar], p);   // positive => valid
            per = a / (a + FEPS) * io;
        } else {
            // multi-assigned: reference resolves by argmax IoU over valid m
            float2 a2 = *(const float2*)&anc[2 * n];
            float bestI = -1.0f; int bestM = 0;
            for (int m = 0; m < MM; ++m) {
                float4 gg = gtb[m];
                float d1 = a2.x - gg.x, d2 = a2.y - gg.y;
                float d3 = gg.z - a2.x, d4 = gg.w - a2.y;
                bool valid = (fminf(fminf(d1, d2), fminf(d3, d4)) > FEPS) &&
                             (mgS[m] > 0.5f);
                float io = valid ? iou_pair(gg, p) : 0.0f;
                if (io > bestI) { bestI = io; bestM = m; }   // first-max wins
            }
            mstar = bestM;
            float io = bestI;
            int lb = labS[mstar]; int lbc = lb > 0 ? lb : 0;
            float x = pd_scores[idx * CC + lbc];
            float s = 1.0f / (1.0f + expf(-x));
            float i2 = io * io;
            float a = s * (i2 * i2 * i2);      // continuous-only recompute
            per = a / (a + FEPS) * io;
        }
    }

    out0[idx] = (float)labS[mstar];
    ((float4*)out1)[idx] = gtb[mstar];
    out3[idx] = fg;
    out4[idx] = (float)mstar;
    perb[idx] = per;
}

// Kernel 3: fused zero + one-hot scatter, dense coalesced float4 writes.
__global__ __launch_bounds__(256) void k_cls(
    const float* __restrict__ out0, const float* __restrict__ perb,
    float4* __restrict__ cls4)
{
    int i = blockIdx.x * 256 + threadIdx.x;      // float4 index, C/4 = 20 per row
    if (i >= BB * NN * CC / 4) return;
    int row = i / 20;
    int c4 = (i - row * 20) * 4;
    int lab = (int)out0[row];
    float per = perb[row];
    int d = lab - c4;
    float4 v;
    v.x = (d == 0) ? per : 0.0f;
    v.y = (d == 1) ? per : 0.0f;
    v.z = (d == 2) ? per : 0.0f;
    v.w = (d == 3) ? per : 0.0f;
    cls4[i] = v;
}

extern "C" void kernel_launch(void* const* d_in, const int* in_sizes, int n_in,
                              void* d_out, int out_size, void* d_ws, size_t ws_size,
                              hipStream_t stream) {
    const float* pd_scores = (const float*)d_in[0];
    const float* pd_bboxes = (const float*)d_in[1];
    const float* anc       = (const float*)d_in[2];
    const int*   gt_labels = (const int*)d_in[3];
    const float* gt_bboxes = (const float*)d_in[4];
    const float* mask_gt   = (const float*)d_in[5];

    float* out  = (float*)d_out;
    float* out0 = out;
    float* out1 = out + OFF_O1;
    float* out2 = out + OFF_O2;
    float* out3 = out + OFF_O3;
    float* out4 = out + OFF_O4;

    // scratch in cls-region tail (overwritten by k_cls at the end)
    float* scr   = out2 + SCR_OFF;
    int*   cntb  = (int*)scr;
    int*   mselb = (int*)(scr + 134400);
    float* aselb = scr + 268800;
    float* perb  = (float*)d_ws;               // B*N floats

    // 0) zero the atomic scratch
    k_zero_scratch<<<dim3((403200 + 255) / 256), dim3(256), 0, stream>>>(
        (int*)scr, 403200);

    // 1) per-(b,m): compact, align, wave top-13, scatter positives
    k_select<<<dim3(BB * MM), dim3(256), 0, stream>>>(
        pd_scores, pd_bboxes, anc, gt_labels, gt_bboxes, mask_gt,
        cntb, mselb, aselb);

    // 2) per-anchor resolution
    k_assign<<<dim3((NN + 255) / 256, BB), dim3(256), 0, stream>>>(
        pd_scores, pd_bboxes, anc, gt_labels, gt_bboxes, mask_gt,
        cntb, mselb, aselb, out0, out1, out3, out4, perb);

    // 3) cls_targets: fused zero + scatter (dense coalesced write)
    const int n4 = (BB * NN * CC) / 4;
    k_cls<<<dim3((n4 + 255) / 256), dim3(256), 0, stream>>>(out0, perb, (float4*)out2);
}

// Round 6
// 62.628 us; speedup vs baseline: 1.0665x; 1.0665x over previous
//
#include <hip/hip_runtime.h>
#include <math.h>

#define BB 16
#define NN 8400
#define CC 80
#define MM 64
#define KTOP 13
#define FEPS 1e-9f
#define CAP 2048   // max valid anchors per (b,m); theoretical max ~1510
#define RPL 32     // selection registers per lane: RPL*64 == CAP

// ---- output layout (floats) ----
#define OFF_O1 134400
#define OFF_O2 672000
#define OFF_O3 11424000
#define OFF_O4 11558400
// scratch (cnt/msel/asel, 3 x B*N) in the TAIL of the cls region; read by
// k_assign, then fully overwritten by k_cls afterwards (stream order).
#define SCR_OFF 10348800   // 10,752,000 - 3*134,400

__device__ __forceinline__ float iou_pair(const float4 g, const float4 p) {
    float ix1 = fmaxf(g.x, p.x);
    float iy1 = fmaxf(g.y, p.y);
    float ix2 = fminf(g.z, p.z);
    float iy2 = fminf(g.w, p.w);
    float iw = fmaxf(ix2 - ix1, 0.0f);
    float ih = fmaxf(iy2 - iy1, 0.0f);
    float inter = iw * ih;
    float aa = (g.z - g.x) * (g.w - g.y);
    float ab = (p.z - p.x) * (p.w - p.y);
    float uni = fmaxf(aa + ab - inter, FEPS);
    return inter / uni;
}

__global__ __launch_bounds__(256) void k_zero_scratch(int* __restrict__ p, int n)
{
    int i = blockIdx.x * 256 + threadIdx.x;
    if (i < n) p[i] = 0;
}

// Kernel 1: one workgroup per (b,m).
//  pass1 (4 waves): in-box test (float4 anchors), ballot-aggregated append.
//  pass2 (4 waves): align metric for compacted entries -> unique composite
//                   (key<<32)|(NN-n) in LDS (order-invariant top-k domain).
//  select (wave 0): load composites into registers ONCE, 13 rounds of
//                   butterfly-max + register removal. No LDS in the loop.
__global__ __launch_bounds__(256) void k_select(
    const float* __restrict__ pd_scores, const float* __restrict__ pd_bboxes,
    const float* __restrict__ anc, const int* __restrict__ gt_labels,
    const float* __restrict__ gt_bboxes, const float* __restrict__ mask_gt,
    int* __restrict__ cntb, int* __restrict__ mselb, float* __restrict__ aselb)
{
    const int bm = blockIdx.x;
    const int b = bm >> 6, m = bm & 63;
    const int tid = threadIdx.x;
    const int lane = tid & 63;
    const int wid = tid >> 6;

    __shared__ unsigned long long k64[CAP];   // 16 KB composites
    __shared__ unsigned short nnidx[CAP];     // 4 KB anchor ids
    __shared__ int scnt;

    const float4 g = *(const float4*)&gt_bboxes[(size_t)bm * 4];
    const int lab  = gt_labels[bm];
    const int labc = lab > 0 ? lab : 0;
    const bool mgb = mask_gt[bm] > 0.5f;
    const unsigned epskey = __float_as_uint(FEPS);

    if (tid == 0) scnt = 0;
    __syncthreads();

    // pass 1: in-box test, 2 anchors per thread-iter, ballot-aggregated append
    const float4* anc4 = (const float4*)anc;   // 4200 entries
    for (int it = 0; it < 17; ++it) {
        int q = it * 256 + tid;
        bool vA = false, vB = false;
        if (q < 4200 && mgb) {
            float4 av = anc4[q];
            {
                float d1 = av.x - g.x, d2 = av.y - g.y;
                float d3 = g.z - av.x, d4 = g.w - av.y;
                vA = fminf(fminf(d1, d2), fminf(d3, d4)) > FEPS;
            }
            {
                float d1 = av.z - g.x, d2 = av.w - g.y;
                float d3 = g.z - av.z, d4 = g.w - av.w;
                vB = fminf(fminf(d1, d2), fminf(d3, d4)) > FEPS;
            }
        }
        unsigned long long balA = __ballot(vA);
        unsigned long long balB = __ballot(vB);
        if (balA | balB) {
            int cA = __popcll(balA);
            int base = 0;
            if (lane == 0) base = atomicAdd(&scnt, cA + __popcll(balB));
            base = __shfl(base, 0, 64);
            unsigned long long below = (1ull << lane) - 1ull;
            if (vA) {
                int s = base + __popcll(balA & below);
                if (s < CAP) nnidx[s] = (unsigned short)(2 * q);
            }
            if (vB) {
                int s = base + cA + __popcll(balB & below);
                if (s < CAP) nnidx[s] = (unsigned short)(2 * q + 1);
            }
        }
    }
    __syncthreads();
    const int count = min(scnt, CAP);

    // pass 2: align metric for compacted entries (~400); composite into k64
    const float* srow = pd_scores + (size_t)b * NN * CC + labc;
    const float* pbb  = pd_bboxes + (size_t)b * NN * 4;
    for (int i = tid; i < count; i += 256) {
        int n = nnidx[i];
        float4 p = *(const float4*)&pbb[(size_t)n * 4];
        float io = iou_pair(g, p);
        float x = srow[(size_t)n * CC];
        float s = 1.0f / (1.0f + expf(-x));
        float i2 = io * io;
        unsigned key = __float_as_uint(s * (i2 * i2 * i2));  // >= 0
        k64[i] = ((unsigned long long)key << 32) | (unsigned)(NN - n);
    }
    __syncthreads();

    // selection: wave 0, all candidates in registers, 13 butterfly rounds
    if (wid == 0) {
        unsigned long long e[RPL];
        #pragma unroll
        for (int j = 0; j < RPL; ++j) {
            int i = lane + j * 64;
            e[j] = (i < count) ? k64[i] : 0ull;   // independent, pipelined
        }
        unsigned long long lm = 0ull;
        #pragma unroll
        for (int j = 0; j < RPL; ++j) if (e[j] > lm) lm = e[j];

        unsigned long long winv = 0ull;
        for (int r = 0; r < KTOP; ++r) {
            unsigned long long bv = lm;
            #pragma unroll
            for (int off = 32; off > 0; off >>= 1) {
                unsigned long long ov = __shfl_xor(bv, off, 64);
                if (ov > bv) bv = ov;
            }
            // bv uniform; stop once best remaining can never be selected
            if ((unsigned)(bv >> 32) <= epskey) break;
            if (lane == r) winv = bv;
            if (lm == bv) {                    // exactly one lane (unique keys)
                #pragma unroll
                for (int j = 0; j < RPL; ++j) if (e[j] == bv) e[j] = 0ull;
                lm = 0ull;
                #pragma unroll
                for (int j = 0; j < RPL; ++j) if (e[j] > lm) lm = e[j];
            }
        }
        if (lane < KTOP) {
            unsigned hk = (unsigned)(winv >> 32);
            if (hk > epskey) {     // positive floats: uint order == float order
                int n = NN - (int)(winv & 0xFFFFFFFFull);
                int ai = b * NN + n;
                atomicAdd(&cntb[ai], 1);
                atomicAdd(&mselb[ai], m);
                atomicAdd(&aselb[ai], __uint_as_float(hk));
            }
        }
    }
}

// Kernel 2: one thread per (b,n). Resolve assignment from scattered positives.
__global__ __launch_bounds__(256) void k_assign(
    const float* __restrict__ pd_scores, const float* __restrict__ pd_bboxes,
    const float* __restrict__ anc, const int* __restrict__ gt_labels,
    const float* __restrict__ gt_bboxes, const float* __restrict__ mask_gt,
    const int* __restrict__ cntb, const int* __restrict__ mselb,
    const float* __restrict__ aselb,
    float* __restrict__ out0, float* __restrict__ out1,
    float* __restrict__ out3, float* __restrict__ out4,
    float* __restrict__ perb)
{
    const int b = blockIdx.y;
    const int n = blockIdx.x * 256 + threadIdx.x;

    __shared__ float4 gtb[MM];
    __shared__ int    labS[MM];
    __shared__ float  mgS[MM];
    if (threadIdx.x < MM) {
        int m = threadIdx.x;
        gtb[m]  = *(const float4*)&gt_bboxes[(size_t)(b * MM + m) * 4];
        labS[m] = gt_labels[b * MM + m];
        mgS[m]  = mask_gt[b * MM + m];
    }
    __syncthreads();
    if (n >= NN) return;

    const size_t idx = (size_t)b * NN + n;
    const int cnt = cntb[idx];

    float per = 0.0f, fg = 0.0f;
    int mstar = 0;

    if (cnt > 0) {
        fg = 1.0f;
        const float4 p = *(const float4*)&pd_bboxes[idx * 4];
        if (cnt == 1) {
            mstar = mselb[idx];
            float a = aselb[idx];
            float io = iou_pair(gtb[mstar], p);   // positive => valid
            per = a / (a + FEPS) * io;
        } else {
            // multi-assigned: reference resolves by argmax IoU over valid m
            float2 a2 = *(const float2*)&anc[2 * n];
            float bestI = -1.0f; int bestM = 0;
            for (int m = 0; m < MM; ++m) {
                float4 gg = gtb[m];
                float d1 = a2.x - gg.x, d2 = a2.y - gg.y;
                float d3 = gg.z - a2.x, d4 = gg.w - a2.y;
                bool valid = (fminf(fminf(d1, d2), fminf(d3, d4)) > FEPS) &&
                             (mgS[m] > 0.5f);
                float io = valid ? iou_pair(gg, p) : 0.0f;
                if (io > bestI) { bestI = io; bestM = m; }   // first-max wins
            }
            mstar = bestM;
            float io = bestI;
            int lb = labS[mstar]; int lbc = lb > 0 ? lb : 0;
            float x = pd_scores[idx * CC + lbc];
            float s = 1.0f / (1.0f + expf(-x));
            float i2 = io * io;
            float a = s * (i2 * i2 * i2);      // continuous-only recompute
            per = a / (a + FEPS) * io;
        }
    }

    out0[idx] = (float)labS[mstar];
    ((float4*)out1)[idx] = gtb[mstar];
    out3[idx] = fg;
    out4[idx] = (float)mstar;
    perb[idx] = per;
}

// Kernel 3: fused zero + one-hot scatter, dense coalesced float4 writes.
__global__ __launch_bounds__(256) void k_cls(
    const float* __restrict__ out0, const float* __restrict__ perb,
    float4* __restrict__ cls4)
{
    int i = blockIdx.x * 256 + threadIdx.x;      // float4 index, C/4 = 20 per row
    if (i >= BB * NN * CC / 4) return;
    int row = i / 20;
    int c4 = (i - row * 20) * 4;
    int lab = (int)out0[row];
    float per = perb[row];
    int d = lab - c4;
    float4 v;
    v.x = (d == 0) ? per : 0.0f;
    v.y = (d == 1) ? per : 0.0f;
    v.z = (d == 2) ? per : 0.0f;
    v.w = (d == 3) ? per : 0.0f;
    cls4[i] = v;
}

extern "C" void kernel_launch(void* const* d_in, const int* in_sizes, int n_in,
                              void* d_out, int out_size, void* d_ws, size_t ws_size,
                              hipStream_t stream) {
    const float* pd_scores = (const float*)d_in[0];
    const float* pd_bboxes = (const float*)d_in[1];
    const float* anc       = (const float*)d_in[2];
    const int*   gt_labels = (const int*)d_in[3];
    const float* gt_bboxes = (const float*)d_in[4];
    const float* mask_gt   = (const float*)d_in[5];

    float* out  = (float*)d_out;
    float* out0 = out;
    float* out1 = out + OFF_O1;
    float* out2 = out + OFF_O2;
    float* out3 = out + OFF_O3;
    float* out4 = out + OFF_O4;

    // scratch in cls-region tail (overwritten by k_cls at the end)
    float* scr   = out2 + SCR_OFF;
    int*   cntb  = (int*)scr;
    int*   mselb = (int*)(scr + 134400);
    float* aselb = scr + 268800;
    float* perb  = (float*)d_ws;               // B*N floats

    // 0) zero the atomic scratch
    k_zero_scratch<<<dim3((403200 + 255) / 256), dim3(256), 0, stream>>>(
        (int*)scr, 403200);

    // 1) per-(b,m): compact, align, register top-13, scatter positives
    k_select<<<dim3(BB * MM), dim3(256), 0, stream>>>(
        pd_scores, pd_bboxes, anc, gt_labels, gt_bboxes, mask_gt,
        cntb, mselb, aselb);

    // 2) per-anchor resolution
    k_assign<<<dim3((NN + 255) / 256, BB), dim3(256), 0, stream>>>(
        pd_scores, pd_bboxes, anc, gt_labels, gt_bboxes, mask_gt,
        cntb, mselb, aselb, out0, out1, out3, out4, perb);

    // 3) cls_targets: fused zero + scatter (dense coalesced write)
    const int n4 = (BB * NN * CC) / 4;
    k_cls<<<dim3((n4 + 255) / 256), dim3(256), 0, stream>>>(out0, perb, (float4*)out2);
}

// Round 7
// 61.576 us; speedup vs baseline: 1.0847x; 1.0171x over previous
//
#include <hip/hip_runtime.h>
#include <math.h>

#define BB 16
#define NN 8400
#define CC 80
#define MM 64
#define KTOP 13
#define FEPS 1e-9f
#define CAP 2048   // max valid anchors per (b,m); theoretical max 1344
#define WSEG 512   // per-wave segment of the candidate list
#define RPW 8      // registers per lane per wave: RPW*64 == WSEG

// ---- output layout (floats) ----
#define OFF_O1 134400
#define OFF_O2 672000
#define OFF_O3 11424000
#define OFF_O4 11558400
// scratch (cnt/msel/asel, 3 x B*N) in the TAIL of the cls region; read by
// k_assign, then fully overwritten by k_cls afterwards (stream order).
#define SCR_OFF 10348800   // 10,752,000 - 3*134,400

__device__ __forceinline__ float iou_pair(const float4 g, const float4 p) {
    float ix1 = fmaxf(g.x, p.x);
    float iy1 = fmaxf(g.y, p.y);
    float ix2 = fminf(g.z, p.z);
    float iy2 = fminf(g.w, p.w);
    float iw = fmaxf(ix2 - ix1, 0.0f);
    float ih = fmaxf(iy2 - iy1, 0.0f);
    float inter = iw * ih;
    float aa = (g.z - g.x) * (g.w - g.y);
    float ab = (p.z - p.x) * (p.w - p.y);
    float uni = fmaxf(aa + ab - inter, FEPS);
    return inter / uni;
}

__global__ __launch_bounds__(256) void k_zero_scratch(int* __restrict__ p, int n)
{
    int i = blockIdx.x * 256 + threadIdx.x;
    if (i < n) p[i] = 0;
}

// Kernel 1: one workgroup per (b,m).
//  pass1 (4 waves): in-box test (float4 anchors), ballot-aggregated append.
//  pass2 (4 waves): align metric for compacted entries -> unique composite
//                   (key<<32)|(NN-n) in LDS (order-invariant top-k domain).
//  select: each wave top-13 of its 512-entry quarter in REGISTERS (8 u64/lane
//          -> no spill), winners to LDS; wave 0 merges 52 -> top-13; emit.
__global__ __launch_bounds__(256) void k_select(
    const float* __restrict__ pd_scores, const float* __restrict__ pd_bboxes,
    const float* __restrict__ anc, const int* __restrict__ gt_labels,
    const float* __restrict__ gt_bboxes, const float* __restrict__ mask_gt,
    int* __restrict__ cntb, int* __restrict__ mselb, float* __restrict__ aselb)
{
    const int bm = blockIdx.x;
    const int b = bm >> 6, m = bm & 63;
    const int tid = threadIdx.x;
    const int lane = tid & 63;
    const int wid = tid >> 6;

    __shared__ unsigned long long k64[CAP];   // 16 KB composites
    __shared__ unsigned short nnidx[CAP];     // 4 KB anchor ids
    __shared__ unsigned long long cand[64];   // 4*13 winners (padded)
    __shared__ int scnt;

    const float4 g = *(const float4*)&gt_bboxes[(size_t)bm * 4];
    const int lab  = gt_labels[bm];
    const int labc = lab > 0 ? lab : 0;
    const bool mgb = mask_gt[bm] > 0.5f;
    const unsigned epskey = __float_as_uint(FEPS);

    if (tid == 0) scnt = 0;
    __syncthreads();

    // pass 1: in-box test, 2 anchors per thread-iter, ballot-aggregated append
    const float4* anc4 = (const float4*)anc;   // 4200 entries
    for (int it = 0; it < 17; ++it) {
        int q = it * 256 + tid;
        bool vA = false, vB = false;
        if (q < 4200 && mgb) {
            float4 av = anc4[q];
            {
                float d1 = av.x - g.x, d2 = av.y - g.y;
                float d3 = g.z - av.x, d4 = g.w - av.y;
                vA = fminf(fminf(d1, d2), fminf(d3, d4)) > FEPS;
            }
            {
                float d1 = av.z - g.x, d2 = av.w - g.y;
                float d3 = g.z - av.z, d4 = g.w - av.w;
                vB = fminf(fminf(d1, d2), fminf(d3, d4)) > FEPS;
            }
        }
        unsigned long long balA = __ballot(vA);
        unsigned long long balB = __ballot(vB);
        if (balA | balB) {
            int cA = __popcll(balA);
            int base = 0;
            if (lane == 0) base = atomicAdd(&scnt, cA + __popcll(balB));
            base = __shfl(base, 0, 64);
            unsigned long long below = (1ull << lane) - 1ull;
            if (vA) {
                int s = base + __popcll(balA & below);
                if (s < CAP) nnidx[s] = (unsigned short)(2 * q);
            }
            if (vB) {
                int s = base + cA + __popcll(balB & below);
                if (s < CAP) nnidx[s] = (unsigned short)(2 * q + 1);
            }
        }
    }
    __syncthreads();
    const int count = min(scnt, CAP);

    // pass 2: align metric for compacted entries (~400); composite into k64
    const float* srow = pd_scores + (size_t)b * NN * CC + labc;
    const float* pbb  = pd_bboxes + (size_t)b * NN * 4;
    for (int i = tid; i < count; i += 256) {
        int n = nnidx[i];
        float4 p = *(const float4*)&pbb[(size_t)n * 4];
        float io = iou_pair(g, p);
        float x = srow[(size_t)n * CC];
        float s = 1.0f / (1.0f + expf(-x));
        float i2 = io * io;
        unsigned key = __float_as_uint(s * (i2 * i2 * i2));  // >= 0
        k64[i] = ((unsigned long long)key << 32) | (unsigned)(NN - n);
    }
    __syncthreads();

    // stage A: every wave selects top-13 of its 512-entry segment (registers)
    {
        const int sbase = wid * WSEG;
        unsigned long long e[RPW];
        #pragma unroll
        for (int j = 0; j < RPW; ++j) {
            int i = sbase + lane + j * 64;
            e[j] = (i < count) ? k64[i] : 0ull;
        }
        unsigned long long lm = 0ull;
        #pragma unroll
        for (int j = 0; j < RPW; ++j) if (e[j] > lm) lm = e[j];

        unsigned long long winv = 0ull;
        for (int r = 0; r < KTOP; ++r) {
            unsigned long long bv = lm;
            #pragma unroll
            for (int off = 32; off > 0; off >>= 1) {
                unsigned long long ov = __shfl_xor(bv, off, 64);
                if (ov > bv) bv = ov;
            }
            if ((unsigned)(bv >> 32) <= epskey) break;   // nothing selectable left
            if (lane == r) winv = bv;
            if (lm == bv) {                    // exactly one lane (unique keys)
                #pragma unroll
                for (int j = 0; j < RPW; ++j) if (e[j] == bv) e[j] = 0ull;
                lm = 0ull;
                #pragma unroll
                for (int j = 0; j < RPW; ++j) if (e[j] > lm) lm = e[j];
            }
        }
        if (lane < KTOP) cand[wid * KTOP + lane] = winv;
        if (wid == 0 && lane >= 4 * KTOP) cand[lane] = 0ull;  // pad 52..63
    }
    __syncthreads();

    // stage B: wave 0 merges the 52 candidates -> global top-13, then emits
    if (wid == 0) {
        unsigned long long v = cand[lane];     // one candidate per lane
        unsigned long long winv = 0ull;
        for (int r = 0; r < KTOP; ++r) {
            unsigned long long bv = v;
            #pragma unroll
            for (int off = 32; off > 0; off >>= 1) {
                unsigned long long ov = __shfl_xor(bv, off, 64);
                if (ov > bv) bv = ov;
            }
            if ((unsigned)(bv >> 32) <= epskey) break;
            if (lane == r) winv = bv;
            if (v == bv) v = 0ull;             // unique -> exactly one lane
        }
        if (lane < KTOP) {
            unsigned hk = (unsigned)(winv >> 32);
            if (hk > epskey) {     // positive floats: uint order == float order
                int n = NN - (int)(winv & 0xFFFFFFFFull);
                int ai = b * NN + n;
                atomicAdd(&cntb[ai], 1);
                atomicAdd(&mselb[ai], m);
                atomicAdd(&aselb[ai], __uint_as_float(hk));
            }
        }
    }
}

// Kernel 2: one thread per (b,n). Resolve assignment from scattered positives.
__global__ __launch_bounds__(256) void k_assign(
    const float* __restrict__ pd_scores, const float* __restrict__ pd_bboxes,
    const float* __restrict__ anc, const int* __restrict__ gt_labels,
    const float* __restrict__ gt_bboxes, const float* __restrict__ mask_gt,
    const int* __restrict__ cntb, const int* __restrict__ mselb,
    const float* __restrict__ aselb,
    float* __restrict__ out0, float* __restrict__ out1,
    float* __restrict__ out3, float* __restrict__ out4,
    float* __restrict__ perb)
{
    const int b = blockIdx.y;
    const int n = blockIdx.x * 256 + threadIdx.x;

    __shared__ float4 gtb[MM];
    __shared__ int    labS[MM];
    __shared__ float  mgS[MM];
    if (threadIdx.x < MM) {
        int m = threadIdx.x;
        gtb[m]  = *(const float4*)&gt_bboxes[(size_t)(b * MM + m) * 4];
        labS[m] = gt_labels[b * MM + m];
        mgS[m]  = mask_gt[b * MM + m];
    }
    __syncthreads();
    if (n >= NN) return;

    const size_t idx = (size_t)b * NN + n;
    const int cnt = cntb[idx];

    float per = 0.0f, fg = 0.0f;
    int mstar = 0;

    if (cnt > 0) {
        fg = 1.0f;
        const float4 p = *(const float4*)&pd_bboxes[idx * 4];
        if (cnt == 1) {
            mstar = mselb[idx];
            float a = aselb[idx];
            float io = iou_pair(gtb[mstar], p);   // positive => valid
            per = a / (a + FEPS) * io;
        } else {
            // multi-assigned: reference resolves by argmax IoU over valid m
            float2 a2 = *(const float2*)&anc[2 * n];
            float bestI = -1.0f; int bestM = 0;
            for (int m = 0; m < MM; ++m) {
                float4 gg = gtb[m];
                float d1 = a2.x - gg.x, d2 = a2.y - gg.y;
                float d3 = gg.z - a2.x, d4 = gg.w - a2.y;
                bool valid = (fminf(fminf(d1, d2), fminf(d3, d4)) > FEPS) &&
                             (mgS[m] > 0.5f);
                float io = valid ? iou_pair(gg, p) : 0.0f;
                if (io > bestI) { bestI = io; bestM = m; }   // first-max wins
            }
            mstar = bestM;
            float io = bestI;
            int lb = labS[mstar]; int lbc = lb > 0 ? lb : 0;
            float x = pd_scores[idx * CC + lbc];
            float s = 1.0f / (1.0f + expf(-x));
            float i2 = io * io;
            float a = s * (i2 * i2 * i2);      // continuous-only recompute
            per = a / (a + FEPS) * io;
        }
    }

    out0[idx] = (float)labS[mstar];
    ((float4*)out1)[idx] = gtb[mstar];
    out3[idx] = fg;
    out4[idx] = (float)mstar;
    perb[idx] = per;
}

// Kernel 3: fused zero + one-hot scatter, dense coalesced float4 writes.
__global__ __launch_bounds__(256) void k_cls(
    const float* __restrict__ out0, const float* __restrict__ perb,
    float4* __restrict__ cls4)
{
    int i = blockIdx.x * 256 + threadIdx.x;      // float4 index, C/4 = 20 per row
    if (i >= BB * NN * CC / 4) return;
    int row = i / 20;
    int c4 = (i - row * 20) * 4;
    int lab = (int)out0[row];
    float per = perb[row];
    int d = lab - c4;
    float4 v;
    v.x = (d == 0) ? per : 0.0f;
    v.y = (d == 1) ? per : 0.0f;
    v.z = (d == 2) ? per : 0.0f;
    v.w = (d == 3) ? per : 0.0f;
    cls4[i] = v;
}

extern "C" void kernel_launch(void* const* d_in, const int* in_sizes, int n_in,
                              void* d_out, int out_size, void* d_ws, size_t ws_size,
                              hipStream_t stream) {
    const float* pd_scores = (const float*)d_in[0];
    const float* pd_bboxes = (const float*)d_in[1];
    const float* anc       = (const float*)d_in[2];
    const int*   gt_labels = (const int*)d_in[3];
    const float* gt_bboxes = (const float*)d_in[4];
    const float* mask_gt   = (const float*)d_in[5];

    float* out  = (float*)d_out;
    float* out0 = out;
    float* out1 = out + OFF_O1;
    float* out2 = out + OFF_O2;
    float* out3 = out + OFF_O3;
    float* out4 = out + OFF_O4;

    // scratch in cls-region tail (overwritten by k_cls at the end)
    float* scr   = out2 + SCR_OFF;
    int*   cntb  = (int*)scr;
    int*   mselb = (int*)(scr + 134400);
    float* aselb = scr + 268800;
    float* perb  = (float*)d_ws;               // B*N floats

    // 0) zero the atomic scratch
    k_zero_scratch<<<dim3((403200 + 255) / 256), dim3(256), 0, stream>>>(
        (int*)scr, 403200);

    // 1) per-(b,m): compact, align, hierarchical register top-13, scatter
    k_select<<<dim3(BB * MM), dim3(256), 0, stream>>>(
        pd_scores, pd_bboxes, anc, gt_labels, gt_bboxes, mask_gt,
        cntb, mselb, aselb);

    // 2) per-anchor resolution
    k_assign<<<dim3((NN + 255) / 256, BB), dim3(256), 0, stream>>>(
        pd_scores, pd_bboxes, anc, gt_labels, gt_bboxes, mask_gt,
        cntb, mselb, aselb, out0, out1, out3, out4, perb);

    // 3) cls_targets: fused zero + scatter (dense coalesced write)
    const int n4 = (BB * NN * CC) / 4;
    k_cls<<<dim3((n4 + 255) / 256), dim3(256), 0, stream>>>(out0, perb, (float4*)out2);
}